// Round 4
// baseline (59.705 us; speedup 1.0000x reference)
//
#include <hip/hip_runtime.h>
#include <math.h>

#define H 1024
#define S 2048
#define B 32

// Kernel 1: v[b,h] = sum_k hidden[b,k] * W[k,h]
// grid 256 = (bg: 16 groups of 2 b) x (hc: 16 chunks of 64 cols)
// 512 threads = (kg = t>>4: 32 k-groups) x (hq = t&15: 16 float4 columns)
__global__ void __launch_bounds__(512)
proj_hidden_kernel(const float* __restrict__ hidden,
                   const float* __restrict__ W,
                   float* __restrict__ v) {
    __shared__ float hs[2][H];          // 8 KB
    __shared__ float part[32][2][64];   // 16 KB
    const int hc = blockIdx.x & 15;
    const int bg = blockIdx.x >> 4;
    const int hq = threadIdx.x & 15;
    const int kg = threadIdx.x >> 4;

    for (int i = threadIdx.x; i < 2 * H; i += 512)
        hs[i >> 10][i & 1023] = hidden[(bg * 2 + (i >> 10)) * H + (i & 1023)];
    __syncthreads();

    const int h = hc * 64 + hq * 4;
    float4 a0 = {0.f, 0.f, 0.f, 0.f};
    float4 a1 = {0.f, 0.f, 0.f, 0.f};
#pragma unroll 4
    for (int kk = 0; kk < 32; ++kk) {
        const int k = kg + 32 * kk;
        const float h0 = hs[0][k];
        const float h1 = hs[1][k];
        const float4 w = *reinterpret_cast<const float4*>(W + (size_t)k * H + h);
        a0.x = fmaf(h0, w.x, a0.x); a0.y = fmaf(h0, w.y, a0.y);
        a0.z = fmaf(h0, w.z, a0.z); a0.w = fmaf(h0, w.w, a0.w);
        a1.x = fmaf(h1, w.x, a1.x); a1.y = fmaf(h1, w.y, a1.y);
        a1.z = fmaf(h1, w.z, a1.z); a1.w = fmaf(h1, w.w, a1.w);
    }
    *reinterpret_cast<float4*>(&part[kg][0][hq * 4]) = a0;
    *reinterpret_cast<float4*>(&part[kg][1][hq * 4]) = a1;
    __syncthreads();

    if (threadIdx.x < 128) {
        const int bb = threadIdx.x >> 6;
        const int c  = threadIdx.x & 63;
        float sum = 0.f;
#pragma unroll 8
        for (int g = 0; g < 32; ++g) sum += part[g][bb][c];
        v[(bg * 2 + bb) * H + hc * 64 + c] = sum;
    }
}

// Kernel 2: scores[b,s] = dot(enc[s,b,:], v[b,:])
// grid = 1024 blocks = (b: 32) x (strip: 32 of 64 s-rows). 256 threads.
// v[b] lives in 16 VGPRs per lane (loaded once). Each wave owns a whole
// enc row per load group: every load is a contiguous 1 KB wave transaction.
// 4 rows in flight per iteration (16 independent float4 loads/lane).
__global__ void __launch_bounds__(256)
scores_kernel(const float* __restrict__ enc,
              const float* __restrict__ v,
              float* __restrict__ scores) {
    const int b     = blockIdx.x & 31;
    const int strip = blockIdx.x >> 5;
    const int wave  = threadIdx.x >> 6;
    const int lane  = threadIdx.x & 63;

    // per-lane fragment of v[b]: lane covers float4 indices lane + 64q
    const float4* vb = reinterpret_cast<const float4*>(v + (size_t)b * H);
    float4 vf0 = vb[lane];
    float4 vf1 = vb[lane + 64];
    float4 vf2 = vb[lane + 128];
    float4 vf3 = vb[lane + 192];

    const int s_base = strip * 64 + wave * 16;   // this wave: 16 rows
    const float4* enc4 = reinterpret_cast<const float4*>(enc);

    for (int i = 0; i < 16; i += 4) {
        const int s = s_base + i;
        const float4* r0 = enc4 + ((size_t)(s + 0) * B + b) * 256;
        const float4* r1 = enc4 + ((size_t)(s + 1) * B + b) * 256;
        const float4* r2 = enc4 + ((size_t)(s + 2) * B + b) * 256;
        const float4* r3 = enc4 + ((size_t)(s + 3) * B + b) * 256;

        float a0 = 0.f, a1 = 0.f, a2 = 0.f, a3 = 0.f;
#define ROWQ(acc, rp, q, vf)                                            \
        {                                                               \
            const float4 e = rp[lane + 64 * q];                         \
            acc = fmaf(e.x, vf.x, fmaf(e.y, vf.y,                       \
                  fmaf(e.z, vf.z, fmaf(e.w, vf.w, acc))));              \
        }
        ROWQ(a0, r0, 0, vf0) ROWQ(a0, r0, 1, vf1) ROWQ(a0, r0, 2, vf2) ROWQ(a0, r0, 3, vf3)
        ROWQ(a1, r1, 0, vf0) ROWQ(a1, r1, 1, vf1) ROWQ(a1, r1, 2, vf2) ROWQ(a1, r1, 3, vf3)
        ROWQ(a2, r2, 0, vf0) ROWQ(a2, r2, 1, vf1) ROWQ(a2, r2, 2, vf2) ROWQ(a2, r2, 3, vf3)
        ROWQ(a3, r3, 0, vf0) ROWQ(a3, r3, 1, vf1) ROWQ(a3, r3, 2, vf2) ROWQ(a3, r3, 3, vf3)
#undef ROWQ

        // four independent 64-lane butterfly reductions (chains interleave)
#pragma unroll
        for (int off = 32; off > 0; off >>= 1) {
            a0 += __shfl_down(a0, off, 64);
            a1 += __shfl_down(a1, off, 64);
            a2 += __shfl_down(a2, off, 64);
            a3 += __shfl_down(a3, off, 64);
        }
        if (lane == 0) {
            float4 r = {a0, a1, a2, a3};
            *reinterpret_cast<float4*>(scores + (size_t)b * S + s) = r;
        }
    }
}

// Kernel 3: out[b, :] = softmax(scores[b, :]) ; one block per b.
__global__ void __launch_bounds__(256)
softmax_kernel(const float* __restrict__ scores,
               float* __restrict__ out) {
    const int b    = blockIdx.x;
    const int tid  = threadIdx.x;
    const int wave = tid >> 6;
    const int lane = tid & 63;

    __shared__ float wmax[4];
    __shared__ float wsum[4];

    float x[8];
    float m = -INFINITY;
#pragma unroll
    for (int i = 0; i < 8; ++i) {
        x[i] = scores[(size_t)b * S + tid + i * 256];
        m = fmaxf(m, x[i]);
    }
#pragma unroll
    for (int off = 32; off > 0; off >>= 1)
        m = fmaxf(m, __shfl_down(m, off, 64));
    if (lane == 0) wmax[wave] = m;
    __syncthreads();
    m = fmaxf(fmaxf(wmax[0], wmax[1]), fmaxf(wmax[2], wmax[3]));

    float sum = 0.f;
#pragma unroll
    for (int i = 0; i < 8; ++i) {
        x[i] = __expf(x[i] - m);
        sum += x[i];
    }
#pragma unroll
    for (int off = 32; off > 0; off >>= 1)
        sum += __shfl_down(sum, off, 64);
    if (lane == 0) wsum[wave] = sum;
    __syncthreads();
    sum = (wsum[0] + wsum[1]) + (wsum[2] + wsum[3]);

    const float inv = 1.0f / sum;
#pragma unroll
    for (int i = 0; i < 8; ++i) {
        out[(size_t)b * S + tid + i * 256] = x[i] * inv;
    }
}

extern "C" void kernel_launch(void* const* d_in, const int* in_sizes, int n_in,
                              void* d_out, int out_size, void* d_ws, size_t ws_size,
                              hipStream_t stream) {
    const float* hidden = (const float*)d_in[0];   // (1, B, H)
    const float* enc    = (const float*)d_in[1];   // (S, B, H)
    const float* W      = (const float*)d_in[2];   // (H, H)
    // d_in[3] = bias: per-b constant shift in scores -> cancelled by softmax.

    float* v      = (float*)d_ws;        // B*H floats
    float* scores = v + (size_t)B * H;   // B*S floats
    float* out    = (float*)d_out;       // B*S floats

    proj_hidden_kernel<<<256, 512, 0, stream>>>(hidden, W, v);
    scores_kernel<<<1024, 256, 0, stream>>>(enc, v, scores);
    softmax_kernel<<<B, 256, 0, stream>>>(scores, out);
}